// Round 3
// baseline (108.842 us; speedup 1.0000x reference)
//
#include <hip/hip_runtime.h>
#include <math.h>

#define CIN   3
#define COUT  16
#define DHW   64

// One thread per TWO output voxels (n,d,h,{2t,2t+1}).
// ConvTranspose3d(k=3,s=2,p=1,op=1) + MaxPool3d(2,2) fused:
//   od = 2*id - 1 + kd  =>  for pooled voxel d (window od in {2d,2d+1}):
//     kd==1 -> even pos (pd=0), id=d ;  kd==0 -> odd (pd=1), id=d+1 ;  kd==2 -> odd (pd=1), id=d
// Each of the 27 taps hits exactly one of the 8 pool positions -> 81 MACs/co/voxel, minimal.
//
// __launch_bounds__(256,2): 256-VGPR cap. Round-2's (256,4) still left the
// allocator at 44 VGPRs vs ~84 live floats -> copy/remat bloat (~6100 VALU
// instrs/thread measured vs ~3100 ideal). Trading occupancy for registers:
// 8 independent FMA chains give enough ILP at 2 waves/SIMD.
__global__ __launch_bounds__(256, 2) void fused_convt_pool_softmax_swish_max(
    const float* __restrict__ x,      // [N,CIN,64,64,64]
    const float* __restrict__ w,      // [CIN,COUT,3,3,3]
    const float* __restrict__ bias,   // [COUT]
    const float* __restrict__ sub,    // [COUT]
    float* __restrict__ out)          // [N,64,64,64]
{
    const int tp = threadIdx.x;                      // w-pair index, 0..31
    const int h  = blockIdx.x * blockDim.y + threadIdx.y;
    const int d  = blockIdx.y;
    const int n  = blockIdx.z;
    const int w0 = tp * 2;                           // outputs w0, w0+1; inputs w0..w0+2

    // x neighborhood: xr[cin][dd][hh][iw-w0], iw in {w0, w0+1, w0+2}
    float xr[CIN][2][2][3];
    const size_t nbase = (size_t)n * CIN * DHW * DHW * DHW;
    const bool w2ok = (w0 + 2 < DHW);
    const int  off2 = w2ok ? 2 : 0;                  // clamped offset: load stays in-bounds
#pragma unroll
    for (int c = 0; c < CIN; ++c) {
#pragma unroll
        for (int dd = 0; dd < 2; ++dd) {
#pragma unroll
            for (int hh = 0; hh < 2; ++hh) {
                const int id = d + dd;
                const int ih = h + hh;
                float v0 = 0.0f, v1 = 0.0f, v2 = 0.0f;
                if (id < DHW && ih < DHW) {          // id uniform per block; ih near-uniform
                    const float* row = x + nbase + (((size_t)c * DHW + id) * DHW + ih) * DHW + w0;
                    const float2 a = *(const float2*)row;     // 8B-aligned (w0 even)
                    v0 = a.x;
                    v1 = a.y;
                    const float t = row[off2];
                    v2 = w2ok ? t : 0.0f;
                }
                xr[c][dd][hh][0] = v0;
                xr[c][dd][hh][1] = v1;
                xr[c][dd][hh][2] = v2;
            }
        }
    }

    float pooled[2][COUT];
#pragma unroll
    for (int co = 0; co < COUT; ++co) {
        float acc[2][2][2][2];                       // [voxel][pd][ph][pw]
#pragma unroll
        for (int v = 0; v < 2; ++v)
#pragma unroll
            for (int i = 0; i < 8; ++i)
                (&acc[v][0][0][0])[i] = 0.0f;
#pragma unroll
        for (int c = 0; c < CIN; ++c) {
            const float* wp = w + ((size_t)(c * COUT + co)) * 27;
#pragma unroll
            for (int kd = 0; kd < 3; ++kd) {
                const int pd = (kd == 1) ? 0 : 1;
                const int dd = (kd == 0) ? 1 : 0;
#pragma unroll
                for (int kh = 0; kh < 3; ++kh) {
                    const int ph = (kh == 1) ? 0 : 1;
                    const int hh = (kh == 0) ? 1 : 0;
#pragma unroll
                    for (int kw = 0; kw < 3; ++kw) {
                        const int pw = (kw == 1) ? 0 : 1;
                        const int ww = (kw == 0) ? 1 : 0;
                        const float wt = wp[kd * 9 + kh * 3 + kw];   // lane-uniform -> s_load
#pragma unroll
                        for (int v = 0; v < 2; ++v)
                            acc[v][pd][ph][pw] =
                                fmaf(wt, xr[c][dd][hh][v + ww], acc[v][pd][ph][pw]);
                    }
                }
            }
        }
        const float bco = bias[co];
#pragma unroll
        for (int v = 0; v < 2; ++v) {
            const float* a = &acc[v][0][0][0];
            const float m0 = fmaxf(fmaxf(a[0], a[1]), a[2]);   // -> v_max3
            const float m1 = fmaxf(fmaxf(a[3], a[4]), a[5]);
            const float m2 = fmaxf(fmaxf(a[6], a[7]), m0);
            pooled[v][co] = fmaxf(m1, m2) + bco;
        }
    }

    // channel softmax + subtract + (single) swish + channel max, per voxel.
    // swish(z)=z*sigmoid(z) is monotone increasing for z > -1.2785; here
    // z = softmax - sub >= -max|sub| ~ -0.3, so max_co swish(z_co) = swish(max_co z_co).
    float res[2];
#pragma unroll
    for (int v = 0; v < 2; ++v) {
        float m = pooled[v][0];
#pragma unroll
        for (int co = 1; co < COUT; ++co) m = fmaxf(m, pooled[v][co]);
        float e[COUT];
        float s = 0.0f;
#pragma unroll
        for (int co = 0; co < COUT; ++co) {
            e[co] = __expf(pooled[v][co] - m);
            s += e[co];
        }
        const float inv = __builtin_amdgcn_rcpf(s);
        float zmax = -3.402823466e+38f;
#pragma unroll
        for (int co = 0; co < COUT; ++co)
            zmax = fmaxf(zmax, fmaf(e[co], inv, -sub[co]));
        res[v] = zmax * __builtin_amdgcn_rcpf(1.0f + __expf(-zmax));
    }

    float* op = out + (((size_t)n * DHW + d) * DHW + h) * DHW + w0;
    *(float2*)op = make_float2(res[0], res[1]);      // coalesced 8B store
}

extern "C" void kernel_launch(void* const* d_in, const int* in_sizes, int n_in,
                              void* d_out, int out_size, void* d_ws, size_t ws_size,
                              hipStream_t stream) {
    const float* x   = (const float*)d_in[0];
    const float* w   = (const float*)d_in[1];
    const float* b   = (const float*)d_in[2];
    const float* sub = (const float*)d_in[3];
    float* out = (float*)d_out;

    dim3 block(32, 8, 1);                 // 32 w-pairs x 8 h-rows = 256 threads
    dim3 grid(DHW / 8, DHW, 4);           // (h-groups, d, n)
    fused_convt_pool_softmax_swish_max<<<grid, block, 0, stream>>>(x, w, b, sub, out);
}

// Round 4
// 108.414 us; speedup vs baseline: 1.0040x; 1.0040x over previous
//
#include <hip/hip_runtime.h>
#include <math.h>

#define CIN   3
#define COUT  16
#define DHW   64

typedef float v2f __attribute__((ext_vector_type(2)));

static __device__ __forceinline__ v2f splat2(float s) { v2f r; r.x = s; r.y = s; return r; }

// One thread per TWO output voxels (n,d,h,{2t,2t+1}), computed as PACKED fp32
// pairs (v_pk_fma_f32 / v_pk_max_f32): both voxels share every weight, so the
// pair is the natural SIMD-within-lane axis. x neighborhood kept as pre-formed
// overlapping pairs so no per-FMA pair-building movs.
//
// ConvTranspose3d(k=3,s=2,p=1,op=1) + MaxPool3d(2,2) fused:
//   od = 2*id - 1 + kd  =>  kd==1 -> even pool pos, id=d ; kd==0 -> odd, id=d+1 ;
//   kd==2 -> odd, id=d.  Each of 27 taps hits exactly one of 8 pool positions.
__global__ __launch_bounds__(256, 2) void fused_convt_pool_softmax_swish_max(
    const float* __restrict__ x,      // [N,CIN,64,64,64]
    const float* __restrict__ w,      // [CIN,COUT,3,3,3]
    const float* __restrict__ bias,   // [COUT]
    const float* __restrict__ sub,    // [COUT]
    float* __restrict__ out)          // [N,64,64,64]
{
    const int tp = threadIdx.x;                      // w-pair index, 0..31
    const int h  = blockIdx.x * blockDim.y + threadIdx.y;
    const int d  = blockIdx.y;
    const int n  = blockIdx.z;
    const int w0 = tp * 2;                           // outputs w0, w0+1; inputs w0..w0+2

    // xp[c][dd][hh][ww] = { x[iw=w0+ww], x[iw=w0+ww+1] } for ww in {0,1}
    v2f xp[CIN][2][2][2];
    const size_t nbase = (size_t)n * CIN * DHW * DHW * DHW;
    const bool w2ok = (w0 + 2 < DHW);
    const int  off2 = w2ok ? 2 : 0;                  // clamped offset: load stays in-bounds
#pragma unroll
    for (int c = 0; c < CIN; ++c) {
#pragma unroll
        for (int dd = 0; dd < 2; ++dd) {
#pragma unroll
            for (int hh = 0; hh < 2; ++hh) {
                const int id = d + dd;
                const int ih = h + hh;
                float v0 = 0.0f, v1 = 0.0f, v2 = 0.0f;
                if (id < DHW && ih < DHW) {          // id uniform per block; ih near-uniform
                    const float* row = x + nbase + (((size_t)c * DHW + id) * DHW + ih) * DHW + w0;
                    const float2 a = *(const float2*)row;     // 8B-aligned (w0 even)
                    v0 = a.x;
                    v1 = a.y;
                    const float t = row[off2];
                    v2 = w2ok ? t : 0.0f;
                }
                v2f p0; p0.x = v0; p0.y = v1;
                v2f p1; p1.x = v1; p1.y = v2;
                xp[c][dd][hh][0] = p0;
                xp[c][dd][hh][1] = p1;
            }
        }
    }

    v2f pooled[COUT];                                // .x = voxel0, .y = voxel1
#pragma unroll
    for (int co = 0; co < COUT; ++co) {
        v2f acc[2][2][2];                            // [pd][ph][pw], packed over voxel
#pragma unroll
        for (int i = 0; i < 8; ++i) (&acc[0][0][0])[i] = splat2(0.0f);
#pragma unroll
        for (int c = 0; c < CIN; ++c) {
            const float* wp = w + ((size_t)(c * COUT + co)) * 27;
#pragma unroll
            for (int kd = 0; kd < 3; ++kd) {
                const int pd = (kd == 1) ? 0 : 1;
                const int dd = (kd == 0) ? 1 : 0;
#pragma unroll
                for (int kh = 0; kh < 3; ++kh) {
                    const int ph = (kh == 1) ? 0 : 1;
                    const int hh = (kh == 0) ? 1 : 0;
#pragma unroll
                    for (int kw = 0; kw < 3; ++kw) {
                        const int pw = (kw == 1) ? 0 : 1;
                        const int ww = (kw == 0) ? 1 : 0;
                        const float wt = wp[kd * 9 + kh * 3 + kw];   // lane-uniform -> s_load
                        acc[pd][ph][pw] = __builtin_elementwise_fma(
                            splat2(wt), xp[c][dd][hh][ww], acc[pd][ph][pw]);
                    }
                }
            }
        }
        const v2f* a = &acc[0][0][0];
        v2f m0 = __builtin_elementwise_max(__builtin_elementwise_max(a[0], a[1]), a[2]);
        v2f m1 = __builtin_elementwise_max(__builtin_elementwise_max(a[3], a[4]), a[5]);
        v2f m2 = __builtin_elementwise_max(__builtin_elementwise_max(a[6], a[7]), m0);
        pooled[co] = __builtin_elementwise_max(m1, m2) + splat2(bias[co]);
    }

    // channel softmax + subtract + swish + channel max, packed over the 2 voxels.
    // swish(z)=z*sigmoid(z) is monotone increasing for z > -1.2785; here
    // z = softmax - sub >= -max|sub| ~ -0.3, so max_co swish(z_co) = swish(max_co z_co).
    v2f m = pooled[0];
#pragma unroll
    for (int co = 1; co < COUT; ++co) m = __builtin_elementwise_max(m, pooled[co]);
    v2f e[COUT];
    v2f s = splat2(0.0f);
#pragma unroll
    for (int co = 0; co < COUT; ++co) {
        v2f t = pooled[co] - m;
        v2f ev; ev.x = __expf(t.x); ev.y = __expf(t.y);
        e[co] = ev;
        s += ev;
    }
    v2f inv; inv.x = __builtin_amdgcn_rcpf(s.x); inv.y = __builtin_amdgcn_rcpf(s.y);
    v2f zmax = splat2(-3.402823466e+38f);
#pragma unroll
    for (int co = 0; co < COUT; ++co)
        zmax = __builtin_elementwise_max(
            zmax, __builtin_elementwise_fma(e[co], inv, splat2(-sub[co])));

    v2f res;
    res.x = zmax.x * __builtin_amdgcn_rcpf(1.0f + __expf(-zmax.x));
    res.y = zmax.y * __builtin_amdgcn_rcpf(1.0f + __expf(-zmax.y));

    float* op = out + (((size_t)n * DHW + d) * DHW + h) * DHW + w0;
    *(v2f*)op = res;                                 // coalesced 8B store
}

extern "C" void kernel_launch(void* const* d_in, const int* in_sizes, int n_in,
                              void* d_out, int out_size, void* d_ws, size_t ws_size,
                              hipStream_t stream) {
    const float* x   = (const float*)d_in[0];
    const float* w   = (const float*)d_in[1];
    const float* b   = (const float*)d_in[2];
    const float* sub = (const float*)d_in[3];
    float* out = (float*)d_out;

    dim3 block(32, 8, 1);                 // 32 w-pairs x 8 h-rows = 256 threads
    dim3 grid(DHW / 8, DHW, 4);           // (h-groups, d, n)
    fused_convt_pool_softmax_swish_max<<<grid, block, 0, stream>>>(x, w, b, sub, out);
}

// Round 5
// 102.634 us; speedup vs baseline: 1.0605x; 1.0563x over previous
//
#include <hip/hip_runtime.h>
#include <math.h>

#define CIN   3
#define COUT  16
#define DHW   64
#define WPAD  28                      // 27 weights padded to 28 -> every group 16B-aligned

typedef float v2f __attribute__((ext_vector_type(2)));

static __device__ __forceinline__ v2f splat2(float s) { v2f r; r.x = s; r.y = s; return r; }

// One thread per TWO output voxels (n,d,h,{2t,2t+1}), packed fp32 math
// (v_pk_fma_f32). Weights staged to LDS once per block and read as
// ds_read_b128 -> results in VGPRs, so the weight pipeline is no longer
// capped by SGPR pressure (rounds 2-4 plateaued at 51us with 48 serialized
// s_load/lgkmcnt stalls per thread; VALU halving moved dur 0%).
//
// ConvTranspose3d(k=3,s=2,p=1,op=1) + MaxPool3d(2,2) fused:
//   od = 2*id - 1 + kd  =>  kd==1 -> even pool pos, id=d ; kd==0 -> odd, id=d+1 ;
//   kd==2 -> odd, id=d.  Each of 27 taps hits exactly one of 8 pool positions.
__global__ __launch_bounds__(256, 4) void fused_convt_pool_softmax_swish_max(
    const float* __restrict__ x,      // [N,CIN,64,64,64]
    const float* __restrict__ w,      // [CIN,COUT,3,3,3]
    const float* __restrict__ bias,   // [COUT]
    const float* __restrict__ sub,    // [COUT]
    float* __restrict__ out)          // [N,64,64,64]
{
    __shared__ float wsm[CIN * COUT * WPAD];         // 48*28*4 = 5376 B

    const int tid = threadIdx.y * 32 + threadIdx.x;
    // Stage weights: 1296 dwords, coalesced; pad slot [27] never read.
    for (int i = tid; i < CIN * COUT * 27; i += 256) {
        const int g = i / 27, r = i - g * 27;
        wsm[g * WPAD + r] = w[i];
    }
    __syncthreads();

    const int tp = threadIdx.x;                      // w-pair index, 0..31
    const int h  = blockIdx.x * blockDim.y + threadIdx.y;
    const int d  = blockIdx.y;
    const int n  = blockIdx.z;
    const int w0 = tp * 2;                           // outputs w0, w0+1; inputs w0..w0+2

    // xp[c][dd][hh][ww] = { x[iw=w0+ww], x[iw=w0+ww+1] } for ww in {0,1}
    v2f xp[CIN][2][2][2];
    const size_t nbase = (size_t)n * CIN * DHW * DHW * DHW;
    const bool w2ok = (w0 + 2 < DHW);
    const int  off2 = w2ok ? 2 : 0;                  // clamped offset: load stays in-bounds
#pragma unroll
    for (int c = 0; c < CIN; ++c) {
#pragma unroll
        for (int dd = 0; dd < 2; ++dd) {
#pragma unroll
            for (int hh = 0; hh < 2; ++hh) {
                const int id = d + dd;
                const int ih = h + hh;
                float v0 = 0.0f, v1 = 0.0f, v2 = 0.0f;
                if (id < DHW && ih < DHW) {
                    const float* row = x + nbase + (((size_t)c * DHW + id) * DHW + ih) * DHW + w0;
                    const float2 a = *(const float2*)row;     // 8B-aligned (w0 even)
                    v0 = a.x;
                    v1 = a.y;
                    const float t = row[off2];
                    v2 = w2ok ? t : 0.0f;
                }
                v2f p0; p0.x = v0; p0.y = v1;
                v2f p1; p1.x = v1; p1.y = v2;
                xp[c][dd][hh][0] = p0;
                xp[c][dd][hh][1] = p1;
            }
        }
    }

    v2f pooled[COUT];                                // .x = voxel0, .y = voxel1
#pragma unroll
    for (int co = 0; co < COUT; ++co) {
        v2f acc[2][2][2];                            // [pd][ph][pw], packed over voxel
#pragma unroll
        for (int i = 0; i < 8; ++i) (&acc[0][0][0])[i] = splat2(0.0f);
#pragma unroll
        for (int c = 0; c < CIN; ++c) {
            // 28-float group, 16B-aligned -> 7x ds_read_b128, results in VGPRs
            const float4* wq = (const float4*)&wsm[(c * COUT + co) * WPAD];
            float4 q[7];
#pragma unroll
            for (int t = 0; t < 7; ++t) q[t] = wq[t];
            const float* wf = (const float*)&q[0];   // wf[0..26] valid
#pragma unroll
            for (int kd = 0; kd < 3; ++kd) {
                const int pd = (kd == 1) ? 0 : 1;
                const int dd = (kd == 0) ? 1 : 0;
#pragma unroll
                for (int kh = 0; kh < 3; ++kh) {
                    const int ph = (kh == 1) ? 0 : 1;
                    const int hh = (kh == 0) ? 1 : 0;
#pragma unroll
                    for (int kw = 0; kw < 3; ++kw) {
                        const int pw = (kw == 1) ? 0 : 1;
                        const int ww = (kw == 0) ? 1 : 0;
                        const float wt = wf[kd * 9 + kh * 3 + kw];   // compile-time q idx
                        acc[pd][ph][pw] = __builtin_elementwise_fma(
                            splat2(wt), xp[c][dd][hh][ww], acc[pd][ph][pw]);
                    }
                }
            }
        }
        const v2f* a = &acc[0][0][0];
        v2f m0 = __builtin_elementwise_max(__builtin_elementwise_max(a[0], a[1]), a[2]);
        v2f m1 = __builtin_elementwise_max(__builtin_elementwise_max(a[3], a[4]), a[5]);
        v2f m2 = __builtin_elementwise_max(__builtin_elementwise_max(a[6], a[7]), m0);
        pooled[co] = __builtin_elementwise_max(m1, m2) + splat2(bias[co]);
    }

    // channel softmax + subtract + swish + channel max, packed over the 2 voxels.
    // swish monotone for z > -1.2785; z = softmax - sub >= -max|sub| ~ -0.3,
    // so max_co swish(z_co) = swish(max_co z_co).
    v2f m = pooled[0];
#pragma unroll
    for (int co = 1; co < COUT; ++co) m = __builtin_elementwise_max(m, pooled[co]);
    v2f e[COUT];
    v2f s = splat2(0.0f);
#pragma unroll
    for (int co = 0; co < COUT; ++co) {
        v2f t = pooled[co] - m;
        v2f ev; ev.x = __expf(t.x); ev.y = __expf(t.y);
        e[co] = ev;
        s += ev;
    }
    v2f inv; inv.x = __builtin_amdgcn_rcpf(s.x); inv.y = __builtin_amdgcn_rcpf(s.y);
    v2f zmax = splat2(-3.402823466e+38f);
#pragma unroll
    for (int co = 0; co < COUT; ++co)
        zmax = __builtin_elementwise_max(
            zmax, __builtin_elementwise_fma(e[co], inv, splat2(-sub[co])));

    v2f res;
    res.x = zmax.x * __builtin_amdgcn_rcpf(1.0f + __expf(-zmax.x));
    res.y = zmax.y * __builtin_amdgcn_rcpf(1.0f + __expf(-zmax.y));

    float* op = out + (((size_t)n * DHW + d) * DHW + h) * DHW + w0;
    *(v2f*)op = res;                                 // coalesced 8B store
}

extern "C" void kernel_launch(void* const* d_in, const int* in_sizes, int n_in,
                              void* d_out, int out_size, void* d_ws, size_t ws_size,
                              hipStream_t stream) {
    const float* x   = (const float*)d_in[0];
    const float* w   = (const float*)d_in[1];
    const float* b   = (const float*)d_in[2];
    const float* sub = (const float*)d_in[3];
    float* out = (float*)d_out;

    dim3 block(32, 8, 1);                 // 32 w-pairs x 8 h-rows = 256 threads
    dim3 grid(DHW / 8, DHW, 4);           // (h-groups, d, n)
    fused_convt_pool_softmax_swish_max<<<grid, block, 0, stream>>>(x, w, b, sub, out);
}